// Round 1
// baseline (1680.972 us; speedup 1.0000x reference)
//
#include <hip/hip_runtime.h>
#include <hip/hip_bf16.h>

#define M_TOT 8192
#define N_TOT 16384
#define K_TOT 4096

typedef __bf16 bf16x8 __attribute__((ext_vector_type(8)));
typedef float f32x4 __attribute__((ext_vector_type(4)));

#define GLOAD_LDS16(g, l)                                                     \
  __builtin_amdgcn_global_load_lds(                                           \
      (__attribute__((address_space(1))) const void*)(g),                     \
      (__attribute__((address_space(3))) void*)(l), 16, 0, 0)

__device__ __forceinline__ ushort f2bf_rne(float f) {
  unsigned u = __float_as_uint(f);
  u += 0x7FFFu + ((u >> 16) & 1u);
  return (ushort)(u >> 16);
}

__device__ __forceinline__ ushort sgn_bf16(float w) {
  // sign(w) in bf16: +1 -> 0x3F80, -1 -> 0xBF80, 0 -> 0
  return w > 0.f ? (ushort)0x3F80u : (w < 0.f ? (ushort)0xBF80u : (ushort)0u);
}

// ---------------- conversion kernels (pass 1) ----------------

__global__ void convert_x_kernel(const float* __restrict__ x,
                                 ushort* __restrict__ xb, int n4) {
  int i = blockIdx.x * blockDim.x + threadIdx.x;
  int stride = gridDim.x * blockDim.x;
  for (; i < n4; i += stride) {
    float4 v = ((const float4*)x)[i];
    ushort4 o;
    o.x = f2bf_rne(v.x);
    o.y = f2bf_rne(v.y);
    o.z = f2bf_rne(v.z);
    o.w = f2bf_rne(v.w);
    ((ushort4*)xb)[i] = o;
  }
}

__global__ void convert_w_kernel(const float* __restrict__ w,
                                 ushort* __restrict__ wb, int n4) {
  int i = blockIdx.x * blockDim.x + threadIdx.x;
  int stride = gridDim.x * blockDim.x;
  for (; i < n4; i += stride) {
    float4 v = ((const float4*)w)[i];
    ushort4 o;
    o.x = sgn_bf16(v.x);
    o.y = sgn_bf16(v.y);
    o.z = sgn_bf16(v.z);
    o.w = sgn_bf16(v.w);
    ((ushort4*)wb)[i] = o;
  }
}

// ---------------- bf16 GEMM (pass 2): C[m][n] = sum_k A[m][k]*B[n][k] + bias[n]
// m97 structure: 128x128 tile, BK=32, 4 waves (2x2 of 64x64), 16x16x32 MFMA,
// global_load_lds width=16, 2-barrier K-loop, XCD-bijective swizzle.

__global__ void gemm_bf16_kernel(const ushort* __restrict__ A,
                                 const ushort* __restrict__ B,
                                 const float* __restrict__ bias,
                                 float* __restrict__ C) {
  __shared__ ushort lsA[128 * 32];
  __shared__ ushort lsB[128 * 32];

  // XCD-aware bijective swizzle (nwg = 8192, divisible by 8)
  int nwg = gridDim.x;
  int bid = blockIdx.x;
  int wg = (bid & 7) * (nwg >> 3) + (bid >> 3);
  const int NBN = N_TOT / 128;  // 128
  int bm = wg / NBN;
  int bn = wg % NBN;
  int rowBase = bm * 128;
  int colBase = bn * 128;

  int t = threadIdx.x;
  int lane = t & 63;
  int wave = t >> 6;
  int wm = (wave >> 1) * 64;  // wave row offset within tile
  int wn = (wave & 1) * 64;   // wave col offset within tile

  f32x4 acc[4][4] = {};

  // staging map: round r (0/1): elem e = r*2048 + t*8
  //   row = r*64 + t/4, col = (t&3)*8   (LDS layout lsA[row*32+col])
  int srow = t >> 2;
  int scol = (t & 3) * 8;
  const ushort* gA0 = A + (size_t)(rowBase + srow) * K_TOT + scol;
  const ushort* gB0 = B + (size_t)(colBase + srow) * K_TOT + scol;
  const size_t r1off = (size_t)64 * K_TOT;
  ushort* lA0 = &lsA[t * 8];
  ushort* lA1 = &lsA[2048 + t * 8];
  ushort* lB0 = &lsB[t * 8];
  ushort* lB1 = &lsB[2048 + t * 8];

  int fr = lane & 15;
  int koff = (lane >> 4) * 8;

  for (int k0 = 0; k0 < K_TOT; k0 += 32) {
    GLOAD_LDS16(gA0 + k0, lA0);
    GLOAD_LDS16(gA0 + r1off + k0, lA1);
    GLOAD_LDS16(gB0 + k0, lB0);
    GLOAD_LDS16(gB0 + r1off + k0, lB1);
    __syncthreads();  // drains vmcnt before barrier (compiler-emitted)

    bf16x8 af[4], bfr[4];
#pragma unroll
    for (int i = 0; i < 4; ++i)
      af[i] = *(const bf16x8*)&lsA[(wm + i * 16 + fr) * 32 + koff];
#pragma unroll
    for (int j = 0; j < 4; ++j)
      bfr[j] = *(const bf16x8*)&lsB[(wn + j * 16 + fr) * 32 + koff];

#pragma unroll
    for (int i = 0; i < 4; ++i)
#pragma unroll
      for (int j = 0; j < 4; ++j)
        acc[i][j] = __builtin_amdgcn_mfma_f32_16x16x32_bf16(af[i], bfr[j],
                                                            acc[i][j], 0, 0, 0);
    __syncthreads();  // protect LDS from next iteration's staging
  }

  // epilogue: C/D layout col = lane&15, row = (lane>>4)*4 + reg
  int orow0 = rowBase + wm + ((lane >> 4) << 2);
  int ocol0 = colBase + wn + (lane & 15);
#pragma unroll
  for (int i = 0; i < 4; ++i) {
#pragma unroll
    for (int j = 0; j < 4; ++j) {
      int col = ocol0 + j * 16;
      float bv = bias[col];
#pragma unroll
      for (int rg = 0; rg < 4; ++rg) {
        int row = orow0 + i * 16 + rg;
        C[(size_t)row * N_TOT + col] = acc[i][j][rg] + bv;
      }
    }
  }
}

// ---------------- fallback: fused fp32->bf16 conversion inside GEMM
// (used only if ws_size is too small for the bf16 staging buffers)

__global__ void gemm_fused_kernel(const float* __restrict__ A,
                                  const float* __restrict__ W,
                                  const float* __restrict__ bias,
                                  float* __restrict__ C) {
  __shared__ ushort lsA[128 * 32];
  __shared__ ushort lsB[128 * 32];

  int nwg = gridDim.x;
  int bid = blockIdx.x;
  int wg = (bid & 7) * (nwg >> 3) + (bid >> 3);
  const int NBN = N_TOT / 128;
  int bm = wg / NBN;
  int bn = wg % NBN;
  int rowBase = bm * 128;
  int colBase = bn * 128;

  int t = threadIdx.x;
  int lane = t & 63;
  int wave = t >> 6;
  int wm = (wave >> 1) * 64;
  int wn = (wave & 1) * 64;

  f32x4 acc[4][4] = {};

  // staging: round r (0..3): e = r*1024 + t*4 ; row = r*32 + t/8 ; col = (t&7)*4
  int srow = t >> 3;
  int scol = (t & 7) * 4;

  int fr = lane & 15;
  int koff = (lane >> 4) * 8;

  for (int k0 = 0; k0 < K_TOT; k0 += 32) {
    float4 va[4], vb[4];
#pragma unroll
    for (int r = 0; r < 4; ++r) {
      va[r] = *(const float4*)&A[(size_t)(rowBase + r * 32 + srow) * K_TOT + k0 + scol];
      vb[r] = *(const float4*)&W[(size_t)(colBase + r * 32 + srow) * K_TOT + k0 + scol];
    }
    __syncthreads();  // previous compute done reading LDS
#pragma unroll
    for (int r = 0; r < 4; ++r) {
      int e = r * 1024 + t * 4;
      ushort4 oa, ob;
      oa.x = f2bf_rne(va[r].x); oa.y = f2bf_rne(va[r].y);
      oa.z = f2bf_rne(va[r].z); oa.w = f2bf_rne(va[r].w);
      ob.x = sgn_bf16(vb[r].x); ob.y = sgn_bf16(vb[r].y);
      ob.z = sgn_bf16(vb[r].z); ob.w = sgn_bf16(vb[r].w);
      *(ushort4*)&lsA[e] = oa;
      *(ushort4*)&lsB[e] = ob;
    }
    __syncthreads();

    bf16x8 af[4], bfr[4];
#pragma unroll
    for (int i = 0; i < 4; ++i)
      af[i] = *(const bf16x8*)&lsA[(wm + i * 16 + fr) * 32 + koff];
#pragma unroll
    for (int j = 0; j < 4; ++j)
      bfr[j] = *(const bf16x8*)&lsB[(wn + j * 16 + fr) * 32 + koff];

#pragma unroll
    for (int i = 0; i < 4; ++i)
#pragma unroll
      for (int j = 0; j < 4; ++j)
        acc[i][j] = __builtin_amdgcn_mfma_f32_16x16x32_bf16(af[i], bfr[j],
                                                            acc[i][j], 0, 0, 0);
  }

  int orow0 = rowBase + wm + ((lane >> 4) << 2);
  int ocol0 = colBase + wn + (lane & 15);
#pragma unroll
  for (int i = 0; i < 4; ++i) {
#pragma unroll
    for (int j = 0; j < 4; ++j) {
      int col = ocol0 + j * 16;
      float bv = bias[col];
#pragma unroll
      for (int rg = 0; rg < 4; ++rg) {
        int row = orow0 + i * 16 + rg;
        C[(size_t)row * N_TOT + col] = acc[i][j][rg] + bv;
      }
    }
  }
}

extern "C" void kernel_launch(void* const* d_in, const int* in_sizes, int n_in,
                              void* d_out, int out_size, void* d_ws,
                              size_t ws_size, hipStream_t stream) {
  const float* x = (const float*)d_in[0];
  const float* W = (const float*)d_in[1];
  const float* b = (const float*)d_in[2];
  float* out = (float*)d_out;

  const size_t xb_elems = (size_t)M_TOT * K_TOT;   // 33.5M
  const size_t wb_elems = (size_t)N_TOT * K_TOT;   // 67.1M
  const size_t need = (xb_elems + wb_elems) * sizeof(ushort);  // ~201.3 MB

  const int nblocks = (M_TOT / 128) * (N_TOT / 128);  // 8192

  if (ws_size >= need) {
    ushort* xb = (ushort*)d_ws;
    ushort* wb = xb + xb_elems;
    convert_x_kernel<<<2048, 256, 0, stream>>>(x, xb, (int)(xb_elems / 4));
    convert_w_kernel<<<2048, 256, 0, stream>>>(W, wb, (int)(wb_elems / 4));
    gemm_bf16_kernel<<<nblocks, 256, 0, stream>>>(xb, wb, b, out);
  } else {
    gemm_fused_kernel<<<nblocks, 256, 0, stream>>>(x, W, b, out);
  }
}

// Round 2
// 1198.813 us; speedup vs baseline: 1.4022x; 1.4022x over previous
//
#include <hip/hip_runtime.h>
#include <hip/hip_bf16.h>

#define M_TOT 8192
#define N_TOT 16384
#define K_TOT 4096
#define BM 256
#define BN 256
#define BK 64
#define NT (K_TOT / BK)  // 64 K-tiles

typedef __bf16 bf16x8 __attribute__((ext_vector_type(8)));
typedef float f32x4 __attribute__((ext_vector_type(4)));

#define GLOAD_LDS16(g, l)                                                     \
  __builtin_amdgcn_global_load_lds(                                           \
      (__attribute__((address_space(1))) const void*)(g),                     \
      (__attribute__((address_space(3))) void*)(l), 16, 0, 0)

__device__ __forceinline__ ushort f2bf_rne(float f) {
  unsigned u = __float_as_uint(f);
  u += 0x7FFFu + ((u >> 16) & 1u);
  return (ushort)(u >> 16);
}

__device__ __forceinline__ ushort sgn_bf16(float w) {
  return w > 0.f ? (ushort)0x3F80u : (w < 0.f ? (ushort)0xBF80u : (ushort)0u);
}

// ---------------- conversion kernels (pass 1) ----------------

__global__ void convert_x_kernel(const float* __restrict__ x,
                                 ushort* __restrict__ xb, int n4) {
  int i = blockIdx.x * blockDim.x + threadIdx.x;
  int stride = gridDim.x * blockDim.x;
  for (; i < n4; i += stride) {
    float4 v = ((const float4*)x)[i];
    ushort4 o;
    o.x = f2bf_rne(v.x);
    o.y = f2bf_rne(v.y);
    o.z = f2bf_rne(v.z);
    o.w = f2bf_rne(v.w);
    ((ushort4*)xb)[i] = o;
  }
}

__global__ void convert_w_kernel(const float* __restrict__ w,
                                 ushort* __restrict__ wb, int n4) {
  int i = blockIdx.x * blockDim.x + threadIdx.x;
  int stride = gridDim.x * blockDim.x;
  for (; i < n4; i += stride) {
    float4 v = ((const float4*)w)[i];
    ushort4 o;
    o.x = sgn_bf16(v.x);
    o.y = sgn_bf16(v.y);
    o.z = sgn_bf16(v.z);
    o.w = sgn_bf16(v.w);
    ((ushort4*)wb)[i] = o;
  }
}

// ---------------- 256x256 8-phase bf16 GEMM (T3+T4+T5) ----------------
// C[m][n] = sum_k A[m][k] * B[n][k] + bias[n]   (B is row-major N x K = B^T)
// 512 threads = 8 waves (2M x 4N). BK=64 split into 2 K-slices of 32.
// LDS: [2 buf][2 ks][2 op][256 rows x 32 cols bf16] = 128 KiB.
// Half-tile = one (ks,op) slab (16 KiB). ds_read of a frag: 64B rows ->
// consecutive rows alternate 128B-window halves -> bank-balanced, no swizzle.
// Stage cadence per tile t (phases p0..p3):
//   p0 reads {A-ks0 mh0, B-ks0}; stages (t+1).A-ks1  (slot last read t-1.p3)
//   p1 reads {A-ks0 mh1};        stages (t+2).B-ks0  (slot last read t.p0)
//   p2 reads {A-ks1 mh0, B-ks1}; stages (t+2).A-ks0  (slot last read t.p1)
//   p3 reads {A-ks1 mh1};        stages (t+2).B-ks1  (slot last read t.p2)
//   p3 tail: s_waitcnt vmcnt(6)  -> tile t+1 fully landed; 3 halves in flight
// Race-free: every overwriting stage is issued after a barrier that follows
// the lgkm-drained last ds_read of that slot.

__global__ __launch_bounds__(512, 2) void gemm_bf16_8phase(
    const ushort* __restrict__ A, const ushort* __restrict__ B,
    const float* __restrict__ bias, float* __restrict__ C) {
  __shared__ ushort lds[2][2][2][8192];  // [buf][ks][op: 0=A 1=B][16KB half]

  int nwg = gridDim.x;  // 2048, divisible by 8
  int bid = blockIdx.x;
  int wg = (bid & 7) * (nwg >> 3) + (bid >> 3);  // XCD-bijective swizzle
  int bm = wg / (N_TOT / BN);
  int bn = wg % (N_TOT / BN);
  int rowBase = bm * BM;
  int colBase = bn * BN;

  int t = threadIdx.x;
  int lane = t & 63;
  int wave = t >> 6;
  int wr = wave >> 2;  // 0..1 -> M half
  int wc = wave & 3;   // 0..3 -> N quarter
  int fr = lane & 15;
  int hi = lane >> 4;

  // staging pointers: thread t loads 16B from row (t>>2), colByte (t&3)*16 of
  // the [128 x 32] sub-slab; q=0/1 covers rows 0-127 / 128-255.
  const ushort* gA0 = A + (size_t)(rowBase + (t >> 2)) * K_TOT + (t & 3) * 8;
  const ushort* gA1 = gA0 + (size_t)128 * K_TOT;
  const ushort* gB0 = B + (size_t)(colBase + (t >> 2)) * K_TOT + (t & 3) * 8;
  const ushort* gB1 = gB0 + (size_t)128 * K_TOT;

  int aoff = (wr * 128 + fr) * 32 + hi * 8;  // ushort offset in A half
  int boff = (wc * 64 + fr) * 32 + hi * 8;   // ushort offset in B half
  int lt = t * 8;                            // staging dest (ushort units)

  f32x4 acc[8][4] = {};

#define STAGE_A(ks_, kt_)                                                     \
  {                                                                           \
    size_t _o = (size_t)(kt_) * 64 + (ks_) * 32;                              \
    GLOAD_LDS16(gA0 + _o, &lds[(kt_) & 1][ks_][0][lt]);                       \
    GLOAD_LDS16(gA1 + _o, &lds[(kt_) & 1][ks_][0][4096 + lt]);                \
  }
#define STAGE_B(ks_, kt_)                                                     \
  {                                                                           \
    size_t _o = (size_t)(kt_) * 64 + (ks_) * 32;                              \
    GLOAD_LDS16(gB0 + _o, &lds[(kt_) & 1][ks_][1][lt]);                       \
    GLOAD_LDS16(gB1 + _o, &lds[(kt_) & 1][ks_][1][4096 + lt]);                \
  }

#define PHASE(ks_, mh_, READB, STAGE_STMT, TAIL_STMT)                         \
  {                                                                           \
    const ushort* _ab = &lds[b][ks_][0][0];                                   \
    _Pragma("unroll") for (int mi = 0; mi < 4; ++mi)                          \
        af[mi] = *(const bf16x8*)(_ab + aoff + ((mh_)*64 + mi * 16) * 32);    \
    if (READB) {                                                              \
      const ushort* _bb = &lds[b][ks_][1][0];                                 \
      _Pragma("unroll") for (int ni = 0; ni < 4; ++ni)                        \
          bfv[ni] = *(const bf16x8*)(_bb + boff + ni * 512);                  \
    }                                                                         \
    STAGE_STMT;                                                               \
    __builtin_amdgcn_s_barrier();                                             \
    __builtin_amdgcn_s_setprio(1);                                            \
    _Pragma("unroll") for (int mi = 0; mi < 4; ++mi)                          \
        _Pragma("unroll") for (int ni = 0; ni < 4; ++ni)                      \
            acc[(mh_)*4 + mi][ni] = __builtin_amdgcn_mfma_f32_16x16x32_bf16(  \
                af[mi], bfv[ni], acc[(mh_)*4 + mi][ni], 0, 0, 0);             \
    __builtin_amdgcn_s_setprio(0);                                            \
    TAIL_STMT;                                                                \
    __builtin_amdgcn_s_barrier();                                             \
  }

  // prologue: tile0 all 4 halves + tile1 {B-ks0, A-ks0, B-ks1}
  STAGE_B(0, 0);
  STAGE_A(0, 0);
  STAGE_B(1, 0);
  STAGE_A(1, 0);
  STAGE_B(0, 1);
  STAGE_A(0, 1);
  STAGE_B(1, 1);
  asm volatile("s_waitcnt vmcnt(6)" ::: "memory");  // tile0 landed
  __builtin_amdgcn_s_barrier();

  for (int tt = 0; tt < NT; ++tt) {
    int b = tt & 1;
    bf16x8 af[4], bfv[4];
    PHASE(0, 0, true, { if (tt + 1 < NT) STAGE_A(1, tt + 1); }, {});
    PHASE(0, 1, false, { if (tt + 2 < NT) STAGE_B(0, tt + 2); }, {});
    PHASE(1, 0, true, { if (tt + 2 < NT) STAGE_A(0, tt + 2); }, {});
    PHASE(1, 1, false, { if (tt + 2 < NT) STAGE_B(1, tt + 2); }, {
      if (tt + 2 < NT) {
        asm volatile("s_waitcnt vmcnt(6)" ::: "memory");
      } else if (tt + 1 < NT) {
        asm volatile("s_waitcnt vmcnt(0)" ::: "memory");
      }
    });
  }

#undef PHASE
#undef STAGE_A
#undef STAGE_B

  // epilogue: C/D layout col = fr, row = hi*4 + rg
#pragma unroll
  for (int mm = 0; mm < 8; ++mm) {
    int row0 = rowBase + wr * 128 + mm * 16 + hi * 4;
#pragma unroll
    for (int ni = 0; ni < 4; ++ni) {
      int col = colBase + wc * 64 + ni * 16 + fr;
      float bv = bias[col];
#pragma unroll
      for (int rg = 0; rg < 4; ++rg)
        C[(size_t)(row0 + rg) * N_TOT + col] = acc[mm][ni][rg] + bv;
    }
  }
}

// ---------------- fallback: fused fp32->bf16 conversion inside GEMM ----------

__global__ void gemm_fused_kernel(const float* __restrict__ A,
                                  const float* __restrict__ W,
                                  const float* __restrict__ bias,
                                  float* __restrict__ C) {
  __shared__ ushort lsA[128 * 32];
  __shared__ ushort lsB[128 * 32];

  int nwg = gridDim.x;
  int bid = blockIdx.x;
  int wg = (bid & 7) * (nwg >> 3) + (bid >> 3);
  const int NBN = N_TOT / 128;
  int bm = wg / NBN;
  int bn = wg % NBN;
  int rowBase = bm * 128;
  int colBase = bn * 128;

  int t = threadIdx.x;
  int lane = t & 63;
  int wave = t >> 6;
  int wm = (wave >> 1) * 64;
  int wn = (wave & 1) * 64;

  f32x4 acc[4][4] = {};

  int srow = t >> 3;
  int scol = (t & 7) * 4;
  int fr = lane & 15;
  int koff = (lane >> 4) * 8;

  for (int k0 = 0; k0 < K_TOT; k0 += 32) {
    float4 va[4], vb[4];
#pragma unroll
    for (int r = 0; r < 4; ++r) {
      va[r] = *(const float4*)&A[(size_t)(rowBase + r * 32 + srow) * K_TOT + k0 + scol];
      vb[r] = *(const float4*)&W[(size_t)(colBase + r * 32 + srow) * K_TOT + k0 + scol];
    }
    __syncthreads();
#pragma unroll
    for (int r = 0; r < 4; ++r) {
      int e = r * 1024 + t * 4;
      ushort4 oa, ob;
      oa.x = f2bf_rne(va[r].x); oa.y = f2bf_rne(va[r].y);
      oa.z = f2bf_rne(va[r].z); oa.w = f2bf_rne(va[r].w);
      ob.x = sgn_bf16(vb[r].x); ob.y = sgn_bf16(vb[r].y);
      ob.z = sgn_bf16(vb[r].z); ob.w = sgn_bf16(vb[r].w);
      *(ushort4*)&lsA[e] = oa;
      *(ushort4*)&lsB[e] = ob;
    }
    __syncthreads();

    bf16x8 af[4], bfr[4];
#pragma unroll
    for (int i = 0; i < 4; ++i)
      af[i] = *(const bf16x8*)&lsA[(wm + i * 16 + fr) * 32 + koff];
#pragma unroll
    for (int j = 0; j < 4; ++j)
      bfr[j] = *(const bf16x8*)&lsB[(wn + j * 16 + fr) * 32 + koff];

#pragma unroll
    for (int i = 0; i < 4; ++i)
#pragma unroll
      for (int j = 0; j < 4; ++j)
        acc[i][j] = __builtin_amdgcn_mfma_f32_16x16x32_bf16(af[i], bfr[j],
                                                            acc[i][j], 0, 0, 0);
  }

  int orow0 = rowBase + wm + ((lane >> 4) << 2);
  int ocol0 = colBase + wn + (lane & 15);
#pragma unroll
  for (int i = 0; i < 4; ++i) {
#pragma unroll
    for (int j = 0; j < 4; ++j) {
      int col = ocol0 + j * 16;
      float bv = bias[col];
#pragma unroll
      for (int rg = 0; rg < 4; ++rg) {
        int row = orow0 + i * 16 + rg;
        C[(size_t)row * N_TOT + col] = acc[i][j][rg] + bv;
      }
    }
  }
}

extern "C" void kernel_launch(void* const* d_in, const int* in_sizes, int n_in,
                              void* d_out, int out_size, void* d_ws,
                              size_t ws_size, hipStream_t stream) {
  const float* x = (const float*)d_in[0];
  const float* W = (const float*)d_in[1];
  const float* b = (const float*)d_in[2];
  float* out = (float*)d_out;

  const size_t xb_elems = (size_t)M_TOT * K_TOT;
  const size_t wb_elems = (size_t)N_TOT * K_TOT;
  const size_t need = (xb_elems + wb_elems) * sizeof(ushort);

  if (ws_size >= need) {
    ushort* xb = (ushort*)d_ws;
    ushort* wb = xb + xb_elems;
    convert_x_kernel<<<2048, 256, 0, stream>>>(x, xb, (int)(xb_elems / 4));
    convert_w_kernel<<<2048, 256, 0, stream>>>(W, wb, (int)(wb_elems / 4));
    const int nblocks = (M_TOT / BM) * (N_TOT / BN);  // 2048
    gemm_bf16_8phase<<<nblocks, 512, 0, stream>>>(xb, wb, b, out);
  } else {
    const int nblocks = (M_TOT / 128) * (N_TOT / 128);
    gemm_fused_kernel<<<nblocks, 256, 0, stream>>>(x, W, b, out);
  }
}